// Round 6
// baseline (523.582 us; speedup 1.0000x reference)
//
#include <hip/hip_runtime.h>

// GridManifoldNetwork, round 6 (= round 4 kernel, resubmitted; R4+R5 benches
// were infra failures - "container failed twice" - hypothesis still untested.
// Audited for container-killers: no OOB (16B loads stay in-table), all float4
// addresses 16B-aligned (even entry offsets + even indices), ws footprint
// identical to R2/R3 which ran fine, graph-capture rules respected).
//
// R3 findings: (1) sc0 L1-bypass neutral -> hash kernels are L2-request-
// throughput bound (16.8M random 8B req / 128 L2 channels ~= 55-70us).
// Lever = request count. (2) dense_mlp regression was my asm vmcnt(0)
// serializing the 4-pt gathers -> back to plain loads.
//
// x-pair merge: hash prime for dim0 is 1, so x-corners (i0, i0+1) with same
// (y,z) sit at entries (i0^b) and ((i0+1)^b). i0 even -> these are a and a^1,
// one aligned 16B block -> 1 dwordx4 instead of 2 dwordx2. Parity is uniform
// per point: even pts 4 req, odd pts 8 req, avg 6 (-25%). Dense levels:
// corners always adjacent; mergeable when i0 even (clamp case i0=res-1 is
// odd -> safe unmerged path).
//
// Levels: res=16,32,64,128,256,512; F=2; T=2^19; levels 3..5 hashed,
// size 2^19 -> & 0x7FFFF. Entry offsets: 0,4096,36864,299008,823296,1347584.

#define HP1 2654435761u
#define HP2 805459861u
#define HMASK ((1u << 19) - 1u)

static __device__ __forceinline__ unsigned umin_(unsigned a, unsigned b) {
    return a < b ? a : b;
}

// One hashed level: trilinear gather from a single 4MB L2-resident table.
__global__ __launch_bounds__(256) void hash_level_kernel(
    const float* __restrict__ x,
    const float2* __restrict__ tab,
    float2* __restrict__ feat,
    float scale, int N)
{
    const int gid = blockIdx.x * 256 + threadIdx.x;
    if (gid >= N) return;

    const float px = __builtin_nontemporal_load(x + 3 * gid + 0);
    const float py = __builtin_nontemporal_load(x + 3 * gid + 1);
    const float pz = __builtin_nontemporal_load(x + 3 * gid + 2);

    const float p0 = fmaf((px + 1.0f) * 0.5f, scale, 0.5f);
    const float p1 = fmaf((py + 1.0f) * 0.5f, scale, 0.5f);
    const float p2 = fmaf((pz + 1.0f) * 0.5f, scale, 0.5f);
    const float g0 = floorf(p0), g1 = floorf(p1), g2 = floorf(p2);
    const float f0 = p0 - g0, f1 = p1 - g1, f2 = p2 - g2;
    const unsigned i0 = (unsigned)g0, i1 = (unsigned)g1, i2 = (unsigned)g2;

    const float wy[2] = {1.0f - f1, f1};
    const float wz[2] = {1.0f - f2, f2};
    const unsigned hy[2] = {i1 * HP1, (i1 + 1u) * HP1};
    const unsigned hz[2] = {i2 * HP2, (i2 + 1u) * HP2};

    unsigned base[4];
    float wyz[4];
    #pragma unroll
    for (int c = 0; c < 4; ++c) {
        const int by = c & 1, bz = c >> 1;
        base[c] = hy[by] ^ hz[bz];
        wyz[c] = wy[by] * wz[bz];
    }

    float2 v0[4], v1[4];   // v0 = corner x=i0, v1 = corner x=i0+1
    if ((i0 & 1u) == 0u) {
        // even: (i0^b) and ((i0+1)^b) = a, a^1 -> one aligned 16B load each
        float4 q[4];
        #pragma unroll
        for (int c = 0; c < 4; ++c) {
            const unsigned pb = ((i0 ^ base[c]) & HMASK) & ~1u;
            q[c] = *(const float4*)(tab + pb);
        }
        #pragma unroll
        for (int c = 0; c < 4; ++c) {
            const bool hi = (base[c] & 1u) != 0u;   // (i0^b)&1 == b&1
            const float2 lo2 = make_float2(q[c].x, q[c].y);
            const float2 hi2 = make_float2(q[c].z, q[c].w);
            v0[c] = hi ? hi2 : lo2;
            v1[c] = hi ? lo2 : hi2;
        }
    } else {
        unsigned a0[4], a1[4];
        #pragma unroll
        for (int c = 0; c < 4; ++c) {
            a0[c] = (i0 ^ base[c]) & HMASK;
            a1[c] = ((i0 + 1u) ^ base[c]) & HMASK;
        }
        #pragma unroll
        for (int c = 0; c < 4; ++c) v0[c] = tab[a0[c]];
        #pragma unroll
        for (int c = 0; c < 4; ++c) v1[c] = tab[a1[c]];
    }

    const float wx0 = 1.0f - f0;
    float acc0 = 0.0f, acc1 = 0.0f;
    #pragma unroll
    for (int c = 0; c < 4; ++c) {
        const float wa = wx0 * wyz[c], wb = f0 * wyz[c];
        acc0 = fmaf(wa, v0[c].x, acc0);
        acc1 = fmaf(wa, v0[c].y, acc1);
        acc0 = fmaf(wb, v1[c].x, acc0);
        acc1 = fmaf(wb, v1[c].y, acc1);
    }
    float* fp = (float*)(feat + gid);
    __builtin_nontemporal_store(acc0, fp + 0);
    __builtin_nontemporal_store(acc1, fp + 1);
}

// Dense trilinear level with x-pair merge (plain loads, compiler-scheduled).
static __device__ __forceinline__ void dense_level(
    const float2* __restrict__ tab, unsigned res,
    float xn0, float xn1, float xn2, float& o0, float& o1)
{
    const float scale = (float)(res - 1);
    const float p0 = fmaf(xn0, scale, 0.5f);
    const float p1 = fmaf(xn1, scale, 0.5f);
    const float p2 = fmaf(xn2, scale, 0.5f);
    const float g0 = floorf(p0), g1 = floorf(p1), g2 = floorf(p2);
    const float f0 = p0 - g0, f1 = p1 - g1, f2 = p2 - g2;
    const unsigned i0 = (unsigned)g0, i1 = (unsigned)g1, i2 = (unsigned)g2;

    const unsigned rm1 = res - 1u;
    const unsigned cx0 = i0;                    // i0 <= res-1 always
    const unsigned cx1 = umin_(i0 + 1u, rm1);
    const unsigned cy[2] = {umin_(i1, rm1) * res, umin_(i1 + 1u, rm1) * res};
    const unsigned cz[2] = {umin_(i2, rm1) * res * res,
                            umin_(i2 + 1u, rm1) * res * res};
    const float wy[2] = {1.0f - f1, f1};
    const float wz[2] = {1.0f - f2, f2};

    unsigned yz[4];
    float wyz[4];
    #pragma unroll
    for (int c = 0; c < 4; ++c) {
        const int by = c & 1, bz = c >> 1;
        yz[c] = cy[by] + cz[bz];
        wyz[c] = wy[by] * wz[bz];
    }

    float2 v0[4], v1[4];
    if ((i0 & 1u) == 0u) {      // cx0 even (yz even) -> aligned 16B pair
        #pragma unroll
        for (int c = 0; c < 4; ++c) {
            const float4 q = *(const float4*)(tab + (cx0 + yz[c]));
            v0[c] = make_float2(q.x, q.y);
            v1[c] = make_float2(q.z, q.w);
        }
    } else {                     // includes clamp case cx1==cx0 (rm1 odd)
        #pragma unroll
        for (int c = 0; c < 4; ++c) v0[c] = tab[cx0 + yz[c]];
        #pragma unroll
        for (int c = 0; c < 4; ++c) v1[c] = tab[cx1 + yz[c]];
    }

    const float wx0 = 1.0f - f0;
    float acc0 = 0.0f, acc1 = 0.0f;
    #pragma unroll
    for (int c = 0; c < 4; ++c) {
        const float wa = wx0 * wyz[c], wb = f0 * wyz[c];
        acc0 = fmaf(wa, v0[c].x, acc0);
        acc1 = fmaf(wa, v0[c].y, acc1);
        acc0 = fmaf(wb, v1[c].x, acc0);
        acc1 = fmaf(wb, v1[c].y, acc1);
    }
    o0 = acc0;
    o1 = acc1;
}

// Dense levels 0..2 (tables 2.3MB, L1/L2-resident) + MLP(15->64->1),
// 4 points/thread (LDS weight reads amortized 4x), plain loads everywhere
// so the compiler pipelines gathers across points.
__global__ __launch_bounds__(256) void dense_mlp_kernel(
    const float* __restrict__ x,
    const float* __restrict__ grid,
    const float2* __restrict__ feat,   // [3][N]: levels 3,4,5
    const float* __restrict__ W0,
    const float* __restrict__ b0,
    const float* __restrict__ W1,
    const float* __restrict__ b1,
    float* __restrict__ out, int N)
{
    __shared__ float sW0T[64 * 16];   // sW0T[j][i] = W0[i*64+j], b0 in i=15
    __shared__ float sW1[64];

    const int tid = threadIdx.x;
    for (int t = tid; t < 960; t += 256) {
        int j = t / 15;
        int i = t - j * 15;
        sW0T[j * 16 + i] = W0[i * 64 + j];
    }
    if (tid < 64) {
        sW0T[tid * 16 + 15] = b0[tid];
        sW1[tid] = W1[tid];
    }
    __syncthreads();

    const int base = blockIdx.x * 1024 + tid;
    const float2* gtab = (const float2*)grid;

    float h[4][16];

    #pragma unroll
    for (int k = 0; k < 4; ++k) {
        const int g = base + 256 * k;
        const int gs = (g < N) ? g : 0;

        const float px = __builtin_nontemporal_load(x + 3 * gs + 0);
        const float py = __builtin_nontemporal_load(x + 3 * gs + 1);
        const float pz = __builtin_nontemporal_load(x + 3 * gs + 2);
        const float xn0 = (px + 1.0f) * 0.5f;
        const float xn1 = (py + 1.0f) * 0.5f;
        const float xn2 = (pz + 1.0f) * 0.5f;

        h[k][0] = px; h[k][1] = py; h[k][2] = pz;
        h[k][15] = 1.0f;

        dense_level(gtab + 0u,     16u, xn0, xn1, xn2, h[k][3], h[k][4]);
        dense_level(gtab + 4096u,  32u, xn0, xn1, xn2, h[k][5], h[k][6]);
        dense_level(gtab + 36864u, 64u, xn0, xn1, xn2, h[k][7], h[k][8]);

        #pragma unroll
        for (int l = 0; l < 3; ++l) {
            const float* fp = (const float*)(feat + (size_t)l * N + gs);
            h[k][9 + 2 * l]  = __builtin_nontemporal_load(fp + 0);
            h[k][10 + 2 * l] = __builtin_nontemporal_load(fp + 1);
        }
    }

    // MLP: out = relu(h @ W0 + b0) @ W1 + b1, bias folded via h[15]=1.
    const float b1v = b1[0];
    float o[4] = {b1v, b1v, b1v, b1v};

    #pragma unroll 2
    for (int j = 0; j < 64; ++j) {
        float4 wv[4];
        const float4* wrow = (const float4*)(sW0T + j * 16);
        wv[0] = wrow[0]; wv[1] = wrow[1]; wv[2] = wrow[2]; wv[3] = wrow[3];
        const float* wf = (const float*)wv;
        const float w1j = sW1[j];
        #pragma unroll
        for (int k = 0; k < 4; ++k) {
            float s = 0.0f;
            #pragma unroll
            for (int i = 0; i < 16; ++i)
                s = fmaf(h[k][i], wf[i], s);
            s = fmaxf(s, 0.0f);
            o[k] = fmaf(s, w1j, o[k]);
        }
    }

    #pragma unroll
    for (int k = 0; k < 4; ++k) {
        const int g = base + 256 * k;
        if (g < N) __builtin_nontemporal_store(o[k], out + g);
    }
}

extern "C" void kernel_launch(void* const* d_in, const int* in_sizes, int n_in,
                              void* d_out, int out_size, void* d_ws, size_t ws_size,
                              hipStream_t stream) {
    const float* x    = (const float*)d_in[0];
    const float* grid = (const float*)d_in[1];
    const float* W0   = (const float*)d_in[2];
    const float* b0   = (const float*)d_in[3];
    const float* W1   = (const float*)d_in[4];
    const float* b1   = (const float*)d_in[5];
    float* out = (float*)d_out;

    const int N = in_sizes[0] / 3;
    const int blocks1 = (N + 255) / 256;
    const int blocks4 = (N + 1023) / 1024;

    const float2* gtab = (const float2*)grid;
    float2* feat = (float2*)d_ws;               // [3][N] float2 = 48MB

    hash_level_kernel<<<blocks1, 256, 0, stream>>>(x, gtab + 299008u,
                                                   feat + (size_t)0 * N, 127.0f, N);
    hash_level_kernel<<<blocks1, 256, 0, stream>>>(x, gtab + 823296u,
                                                   feat + (size_t)1 * N, 255.0f, N);
    hash_level_kernel<<<blocks1, 256, 0, stream>>>(x, gtab + 1347584u,
                                                   feat + (size_t)2 * N, 511.0f, N);
    dense_mlp_kernel<<<blocks4, 256, 0, stream>>>(x, grid, feat, W0, b0, W1, b1,
                                                  out, N);
}

// Round 7
// 370.863 us; speedup vs baseline: 1.4118x; 1.4118x over previous
//
#include <hip/hip_runtime.h>

// GridManifoldNetwork, round 7.
// R6 verdicts: (1) x-pair merge neutral->regressive; with sc0 also neutral,
// the fitting model is L2 line-fill BW (~15 TB/s random): line count is
// hash-random and irreducible -> hash kernels at ~71us/level are the wall;
// revert to R2's simple 8x dwordx2 form. (2) dense_mlp must avoid both the
// DS pipe (R2: 256 broadcast ds_read_b128/wave = 164us pipe time) and
// register blowup (R6: VGPR 160). This round: 4 pts/thread + weights via
// SMEM pipe (s_load of pre-transposed W0T rows, SGPR-operand v_fma), zero
// LDS, __launch_bounds__(256,4) caps VGPR at 128.
// feat staged as packed bf16x2 (halves feat traffic; error ~4e-5 << 2.5e-2).
//
// Levels: res=16,32,64,128,256,512; F=2; T=2^19; levels 3..5 hashed,
// size 2^19 -> & 0x7FFFF. Entry offsets: 0,4096,36864,299008,823296,1347584.

#define HP1 2654435761u
#define HP2 805459861u
#define HMASK ((1u << 19) - 1u)

static __device__ __forceinline__ unsigned umin_(unsigned a, unsigned b) {
    return a < b ? a : b;
}

// bf16 round-to-nearest-even pack/unpack (header-version-proof).
static __device__ __forceinline__ unsigned f2bf(float f) {
    unsigned u = __float_as_uint(f);
    return (u + 0x7fffu + ((u >> 16) & 1u)) >> 16;
}
static __device__ __forceinline__ float bf2f_lo(unsigned p) {
    return __uint_as_float((p & 0xffffu) << 16);
}
static __device__ __forceinline__ float bf2f_hi(unsigned p) {
    return __uint_as_float(p & 0xffff0000u);
}

// Prep: wt[0..1023] = W0T rows (wt[j*16+i] = W0[i*64+j], i=15 -> b0[j]);
// wt[1024..1087] = W1; wt[1088] = b1.
__global__ __launch_bounds__(256) void prep_kernel(
    const float* __restrict__ W0, const float* __restrict__ b0,
    const float* __restrict__ W1, const float* __restrict__ b1,
    float* __restrict__ wt)
{
    for (int t = threadIdx.x; t < 1024; t += 256) {
        const int j = t >> 4, i = t & 15;
        wt[t] = (i == 15) ? b0[j] : W0[i * 64 + j];
    }
    if (threadIdx.x < 64) wt[1024 + threadIdx.x] = W1[threadIdx.x];
    if (threadIdx.x == 0) wt[1088] = b1[0];
}

// One hashed level: 8 divergent 8B gathers from a 4MB L2-resident table
// (R2 form — proven 71us; L2 line-fill-BW-bound, irreducible).
__global__ __launch_bounds__(256) void hash_level_kernel(
    const float* __restrict__ x,
    const float2* __restrict__ tab,
    unsigned* __restrict__ feat,      // packed bf16x2 per point
    float scale, int N)
{
    const int gid = blockIdx.x * 256 + threadIdx.x;
    if (gid >= N) return;

    const float px = __builtin_nontemporal_load(x + 3 * gid + 0);
    const float py = __builtin_nontemporal_load(x + 3 * gid + 1);
    const float pz = __builtin_nontemporal_load(x + 3 * gid + 2);

    const float p0 = fmaf((px + 1.0f) * 0.5f, scale, 0.5f);
    const float p1 = fmaf((py + 1.0f) * 0.5f, scale, 0.5f);
    const float p2 = fmaf((pz + 1.0f) * 0.5f, scale, 0.5f);
    const float g0 = floorf(p0), g1 = floorf(p1), g2 = floorf(p2);
    const float f0 = p0 - g0, f1 = p1 - g1, f2 = p2 - g2;
    const unsigned i0 = (unsigned)g0, i1 = (unsigned)g1, i2 = (unsigned)g2;

    const float wx[2] = {1.0f - f0, f0};
    const float wy[2] = {1.0f - f1, f1};
    const float wz[2] = {1.0f - f2, f2};
    const unsigned hx[2] = {i0, i0 + 1u};
    const unsigned hy[2] = {i1 * HP1, (i1 + 1u) * HP1};
    const unsigned hz[2] = {i2 * HP2, (i2 + 1u) * HP2};

    unsigned idx[8];
    float w[8];
    #pragma unroll
    for (int c = 0; c < 8; ++c) {
        const int bx = c & 1, by = (c >> 1) & 1, bz = (c >> 2) & 1;
        idx[c] = (hx[bx] ^ hy[by] ^ hz[bz]) & HMASK;
        w[c] = wx[bx] * wy[by] * wz[bz];
    }
    float2 v[8];
    #pragma unroll
    for (int c = 0; c < 8; ++c) v[c] = tab[idx[c]];

    float a0 = 0.0f, a1 = 0.0f;
    #pragma unroll
    for (int c = 0; c < 8; ++c) {
        a0 = fmaf(w[c], v[c].x, a0);
        a1 = fmaf(w[c], v[c].y, a1);
    }
    __builtin_nontemporal_store(f2bf(a0) | (f2bf(a1) << 16), feat + gid);
}

// Dense trilinear level, straight-line 8 loads (no branches: R6 showed the
// even/odd merge branch doubles liveness -> VGPR 160).
static __device__ __forceinline__ void dense_level(
    const float2* __restrict__ tab, unsigned res,
    float xn0, float xn1, float xn2, float& o0, float& o1)
{
    const float scale = (float)(res - 1);
    const float p0 = fmaf(xn0, scale, 0.5f);
    const float p1 = fmaf(xn1, scale, 0.5f);
    const float p2 = fmaf(xn2, scale, 0.5f);
    const float g0 = floorf(p0), g1 = floorf(p1), g2 = floorf(p2);
    const float f0 = p0 - g0, f1 = p1 - g1, f2 = p2 - g2;
    const unsigned i0 = (unsigned)g0, i1 = (unsigned)g1, i2 = (unsigned)g2;

    const unsigned rm1 = res - 1u;
    const unsigned cx[2] = {umin_(i0, rm1), umin_(i0 + 1u, rm1)};
    const unsigned cy[2] = {umin_(i1, rm1) * res, umin_(i1 + 1u, rm1) * res};
    const unsigned cz[2] = {umin_(i2, rm1) * res * res,
                            umin_(i2 + 1u, rm1) * res * res};
    const float wx[2] = {1.0f - f0, f0};
    const float wy[2] = {1.0f - f1, f1};
    const float wz[2] = {1.0f - f2, f2};

    float a0 = 0.0f, a1 = 0.0f;
    #pragma unroll
    for (int c = 0; c < 8; ++c) {
        const int bx = c & 1, by = (c >> 1) & 1, bz = (c >> 2) & 1;
        const unsigned idx = cx[bx] + cy[by] + cz[bz];
        const float w = wx[bx] * wy[by] * wz[bz];
        const float2 v = tab[idx];
        a0 = fmaf(w, v.x, a0);
        a1 = fmaf(w, v.y, a1);
    }
    o0 = a0;
    o1 = a1;
}

// Dense levels 0..2 + MLP(15->64->1), 4 points/thread, ZERO LDS:
// weight rows come from the SMEM pipe (uniform j -> s_load_dwordx16 of
// wt+j*16), consumed as SGPR operands in v_fma. launch_bounds(256,4)
// caps VGPR at 128 (h[4][16]=64 VGPR + working set).
__global__ __launch_bounds__(256, 4) void dense_mlp_kernel(
    const float* __restrict__ x,
    const float* __restrict__ grid,
    const unsigned* __restrict__ feat,   // [3][N] packed bf16x2
    const float* __restrict__ wt,        // 1089 floats, see prep_kernel
    float* __restrict__ out, int N)
{
    const int tid = threadIdx.x;
    const int base = blockIdx.x * 1024 + tid;
    const float2* gtab = (const float2*)grid;

    float h[4][16];

    #pragma unroll
    for (int k = 0; k < 4; ++k) {
        const int g = base + 256 * k;
        const int gs = (g < N) ? g : 0;

        const float px = __builtin_nontemporal_load(x + 3 * gs + 0);
        const float py = __builtin_nontemporal_load(x + 3 * gs + 1);
        const float pz = __builtin_nontemporal_load(x + 3 * gs + 2);
        const float xn0 = (px + 1.0f) * 0.5f;
        const float xn1 = (py + 1.0f) * 0.5f;
        const float xn2 = (pz + 1.0f) * 0.5f;

        h[k][0] = px; h[k][1] = py; h[k][2] = pz;
        h[k][15] = 1.0f;

        dense_level(gtab + 0u,     16u, xn0, xn1, xn2, h[k][3], h[k][4]);
        dense_level(gtab + 4096u,  32u, xn0, xn1, xn2, h[k][5], h[k][6]);
        dense_level(gtab + 36864u, 64u, xn0, xn1, xn2, h[k][7], h[k][8]);

        #pragma unroll
        for (int l = 0; l < 3; ++l) {
            const unsigned p = __builtin_nontemporal_load(
                feat + (size_t)l * N + gs);
            h[k][9 + 2 * l]  = bf2f_lo(p);
            h[k][10 + 2 * l] = bf2f_hi(p);
        }
    }

    // MLP: out = relu(h @ W0 + b0) @ W1 + b1 (bias folded via h[15]=1).
    const float b1v = wt[1088];
    float o[4] = {b1v, b1v, b1v, b1v};

    #pragma unroll 4
    for (int j = 0; j < 64; ++j) {
        float r[16];
        #pragma unroll
        for (int i = 0; i < 16; ++i)
            r[i] = wt[j * 16 + i];          // uniform -> s_load (SMEM pipe)
        const float w1j = wt[1024 + j];      // uniform -> s_load
        #pragma unroll
        for (int k = 0; k < 4; ++k) {
            float s = 0.0f;
            #pragma unroll
            for (int i = 0; i < 16; ++i)
                s = fmaf(h[k][i], r[i], s);  // v_fma with SGPR weight
            s = fmaxf(s, 0.0f);
            o[k] = fmaf(s, w1j, o[k]);
        }
    }

    #pragma unroll
    for (int k = 0; k < 4; ++k) {
        const int g = base + 256 * k;
        if (g < N) __builtin_nontemporal_store(o[k], out + g);
    }
}

extern "C" void kernel_launch(void* const* d_in, const int* in_sizes, int n_in,
                              void* d_out, int out_size, void* d_ws, size_t ws_size,
                              hipStream_t stream) {
    const float* x    = (const float*)d_in[0];
    const float* grid = (const float*)d_in[1];
    const float* W0   = (const float*)d_in[2];
    const float* b0   = (const float*)d_in[3];
    const float* W1   = (const float*)d_in[4];
    const float* b1   = (const float*)d_in[5];
    float* out = (float*)d_out;

    const int N = in_sizes[0] / 3;
    const int blocks1 = (N + 255) / 256;
    const int blocks4 = (N + 1023) / 1024;

    const float2* gtab = (const float2*)grid;
    unsigned* feat = (unsigned*)d_ws;                      // [3][N] bf16x2 = 24MB
    const size_t feat_bytes = ((size_t)3 * N * 4 + 255) & ~(size_t)255;
    float* wt = (float*)((char*)d_ws + feat_bytes);        // 1089 floats

    prep_kernel<<<1, 256, 0, stream>>>(W0, b0, W1, b1, wt);

    hash_level_kernel<<<blocks1, 256, 0, stream>>>(x, gtab + 299008u,
                                                   feat + (size_t)0 * N, 127.0f, N);
    hash_level_kernel<<<blocks1, 256, 0, stream>>>(x, gtab + 823296u,
                                                   feat + (size_t)1 * N, 255.0f, N);
    hash_level_kernel<<<blocks1, 256, 0, stream>>>(x, gtab + 1347584u,
                                                   feat + (size_t)2 * N, 511.0f, N);
    dense_mlp_kernel<<<blocks4, 256, 0, stream>>>(x, grid, feat, wt, out, N);
}

// Round 8
// 356.789 us; speedup vs baseline: 1.4675x; 1.0394x over previous
//
#include <hip/hip_runtime.h>

// GridManifoldNetwork, round 8.
// R7 insight: R2 (LDS MLP) == R7 (SMEM MLP) == ~150us -> the MLP is hidden
// under dense-level gathers. Unified model: all kernels sit at the L2/TCP
// random-gather wall (~0.24M req/us chip): hash 16.8M req -> 71us,
// dense_mlp ~50M req (partial L1 hits) -> 151us.
// R8 levers: (1) hash 2pt/thread (2x MLP: latency-vs-throughput test);
// (2) dense_mlp stages level-0 (32KB) in LDS -> 16.8M requests move from
// the contended TCP path to the idle DS pipe.
//
// Levels: res=16,32,64,128,256,512; F=2; T=2^19; levels 3..5 hashed,
// size 2^19 -> & 0x7FFFF. Entry offsets: 0,4096,36864,299008,823296,1347584.

#define HP1 2654435761u
#define HP2 805459861u
#define HMASK ((1u << 19) - 1u)

static __device__ __forceinline__ unsigned umin_(unsigned a, unsigned b) {
    return a < b ? a : b;
}

// bf16 round-to-nearest-even pack/unpack.
static __device__ __forceinline__ unsigned f2bf(float f) {
    unsigned u = __float_as_uint(f);
    return (u + 0x7fffu + ((u >> 16) & 1u)) >> 16;
}
static __device__ __forceinline__ float bf2f_lo(unsigned p) {
    return __uint_as_float((p & 0xffffu) << 16);
}
static __device__ __forceinline__ float bf2f_hi(unsigned p) {
    return __uint_as_float(p & 0xffff0000u);
}

// Prep: wt[0..1023] = W0T rows (wt[j*16+i] = W0[i*64+j], i=15 -> b0[j]);
// wt[1024..1087] = W1; wt[1088] = b1.
__global__ __launch_bounds__(256) void prep_kernel(
    const float* __restrict__ W0, const float* __restrict__ b0,
    const float* __restrict__ W1, const float* __restrict__ b1,
    float* __restrict__ wt)
{
    for (int t = threadIdx.x; t < 1024; t += 256) {
        const int j = t >> 4, i = t & 15;
        wt[t] = (i == 15) ? b0[j] : W0[i * 64 + j];
    }
    if (threadIdx.x < 64) wt[1024 + threadIdx.x] = W1[threadIdx.x];
    if (threadIdx.x == 0) wt[1088] = b1[0];
}

// Core of one hashed-level point: 8 divergent 8B gathers + trilerp.
static __device__ __forceinline__ unsigned hash_point(
    const float* __restrict__ x, const float2* __restrict__ tab,
    float scale, int gid)
{
    const float px = __builtin_nontemporal_load(x + 3 * gid + 0);
    const float py = __builtin_nontemporal_load(x + 3 * gid + 1);
    const float pz = __builtin_nontemporal_load(x + 3 * gid + 2);

    const float p0 = fmaf((px + 1.0f) * 0.5f, scale, 0.5f);
    const float p1 = fmaf((py + 1.0f) * 0.5f, scale, 0.5f);
    const float p2 = fmaf((pz + 1.0f) * 0.5f, scale, 0.5f);
    const float g0 = floorf(p0), g1 = floorf(p1), g2 = floorf(p2);
    const float f0 = p0 - g0, f1 = p1 - g1, f2 = p2 - g2;
    const unsigned i0 = (unsigned)g0, i1 = (unsigned)g1, i2 = (unsigned)g2;

    const float wx[2] = {1.0f - f0, f0};
    const float wy[2] = {1.0f - f1, f1};
    const float wz[2] = {1.0f - f2, f2};
    const unsigned hx[2] = {i0, i0 + 1u};
    const unsigned hy[2] = {i1 * HP1, (i1 + 1u) * HP1};
    const unsigned hz[2] = {i2 * HP2, (i2 + 1u) * HP2};

    unsigned idx[8];
    float w[8];
    #pragma unroll
    for (int c = 0; c < 8; ++c) {
        const int bx = c & 1, by = (c >> 1) & 1, bz = (c >> 2) & 1;
        idx[c] = (hx[bx] ^ hy[by] ^ hz[bz]) & HMASK;
        w[c] = wx[bx] * wy[by] * wz[bz];
    }
    float2 v[8];
    #pragma unroll
    for (int c = 0; c < 8; ++c) v[c] = tab[idx[c]];

    float a0 = 0.0f, a1 = 0.0f;
    #pragma unroll
    for (int c = 0; c < 8; ++c) {
        a0 = fmaf(w[c], v[c].x, a0);
        a1 = fmaf(w[c], v[c].y, a1);
    }
    return f2bf(a0) | (f2bf(a1) << 16);
}

// One hashed level, 2 points/thread (16 gathers in flight: tests whether
// the 71us/level wall is latency-occupancy or channel throughput).
__global__ __launch_bounds__(256) void hash_level_kernel(
    const float* __restrict__ x,
    const float2* __restrict__ tab,
    unsigned* __restrict__ feat,      // packed bf16x2 per point
    float scale, int N)
{
    const int g0 = blockIdx.x * 512 + threadIdx.x;
    const int g1 = g0 + 256;
    const int s0 = (g0 < N) ? g0 : 0;
    const int s1 = (g1 < N) ? g1 : 0;

    const unsigned r0 = hash_point(x, tab, scale, s0);
    const unsigned r1 = hash_point(x, tab, scale, s1);

    if (g0 < N) __builtin_nontemporal_store(r0, feat + g0);
    if (g1 < N) __builtin_nontemporal_store(r1, feat + g1);
}

// Dense trilinear level from global (levels 1,2).
static __device__ __forceinline__ void dense_level(
    const float2* __restrict__ tab, unsigned res,
    float xn0, float xn1, float xn2, float& o0, float& o1)
{
    const float scale = (float)(res - 1);
    const float p0 = fmaf(xn0, scale, 0.5f);
    const float p1 = fmaf(xn1, scale, 0.5f);
    const float p2 = fmaf(xn2, scale, 0.5f);
    const float g0 = floorf(p0), g1 = floorf(p1), g2 = floorf(p2);
    const float f0 = p0 - g0, f1 = p1 - g1, f2 = p2 - g2;
    const unsigned i0 = (unsigned)g0, i1 = (unsigned)g1, i2 = (unsigned)g2;

    const unsigned rm1 = res - 1u;
    const unsigned cx[2] = {umin_(i0, rm1), umin_(i0 + 1u, rm1)};
    const unsigned cy[2] = {umin_(i1, rm1) * res, umin_(i1 + 1u, rm1) * res};
    const unsigned cz[2] = {umin_(i2, rm1) * res * res,
                            umin_(i2 + 1u, rm1) * res * res};
    const float wx[2] = {1.0f - f0, f0};
    const float wy[2] = {1.0f - f1, f1};
    const float wz[2] = {1.0f - f2, f2};

    float a0 = 0.0f, a1 = 0.0f;
    #pragma unroll
    for (int c = 0; c < 8; ++c) {
        const int bx = c & 1, by = (c >> 1) & 1, bz = (c >> 2) & 1;
        const unsigned idx = cx[bx] + cy[by] + cz[bz];
        const float w = wx[bx] * wy[by] * wz[bz];
        const float2 v = tab[idx];
        a0 = fmaf(w, v.x, a0);
        a1 = fmaf(w, v.y, a1);
    }
    o0 = a0;
    o1 = a1;
}

// Level 0 (16^3) from LDS — DS pipe is otherwise idle in this kernel.
static __device__ __forceinline__ void dense_level0_lds(
    const float2* __restrict__ sL0,
    float xn0, float xn1, float xn2, float& o0, float& o1)
{
    const float p0 = fmaf(xn0, 15.0f, 0.5f);
    const float p1 = fmaf(xn1, 15.0f, 0.5f);
    const float p2 = fmaf(xn2, 15.0f, 0.5f);
    const float g0 = floorf(p0), g1 = floorf(p1), g2 = floorf(p2);
    const float f0 = p0 - g0, f1 = p1 - g1, f2 = p2 - g2;
    const unsigned i0 = (unsigned)g0, i1 = (unsigned)g1, i2 = (unsigned)g2;

    const unsigned cx[2] = {umin_(i0, 15u), umin_(i0 + 1u, 15u)};
    const unsigned cy[2] = {umin_(i1, 15u) * 16u, umin_(i1 + 1u, 15u) * 16u};
    const unsigned cz[2] = {umin_(i2, 15u) * 256u, umin_(i2 + 1u, 15u) * 256u};
    const float wx[2] = {1.0f - f0, f0};
    const float wy[2] = {1.0f - f1, f1};
    const float wz[2] = {1.0f - f2, f2};

    float a0 = 0.0f, a1 = 0.0f;
    #pragma unroll
    for (int c = 0; c < 8; ++c) {
        const int bx = c & 1, by = (c >> 1) & 1, bz = (c >> 2) & 1;
        const float2 v = sL0[cx[bx] + cy[by] + cz[bz]];
        const float w = wx[bx] * wy[by] * wz[bz];
        a0 = fmaf(w, v.x, a0);
        a1 = fmaf(w, v.y, a1);
    }
    o0 = a0;
    o1 = a1;
}

// Dense levels + MLP, 4 points/thread. Level 0 via LDS (32KB), levels 1,2
// via TCP, weights via SMEM pipe (R7 structure: VGPR 36, occ 53%).
__global__ __launch_bounds__(256, 4) void dense_mlp_kernel(
    const float* __restrict__ x,
    const float* __restrict__ grid,
    const unsigned* __restrict__ feat,   // [3][N] packed bf16x2
    const float* __restrict__ wt,        // 1089 floats, see prep_kernel
    float* __restrict__ out, int N)
{
    __shared__ float2 sL0[4096];          // level-0 table, 32KB

    const int tid = threadIdx.x;
    const float2* gtab = (const float2*)grid;

    #pragma unroll
    for (int t = 0; t < 16; ++t)          // 4096 entries / 256 threads
        sL0[t * 256 + tid] = gtab[t * 256 + tid];
    __syncthreads();

    const int base = blockIdx.x * 1024 + tid;

    float h[4][16];

    #pragma unroll
    for (int k = 0; k < 4; ++k) {
        const int g = base + 256 * k;
        const int gs = (g < N) ? g : 0;

        const float px = __builtin_nontemporal_load(x + 3 * gs + 0);
        const float py = __builtin_nontemporal_load(x + 3 * gs + 1);
        const float pz = __builtin_nontemporal_load(x + 3 * gs + 2);
        const float xn0 = (px + 1.0f) * 0.5f;
        const float xn1 = (py + 1.0f) * 0.5f;
        const float xn2 = (pz + 1.0f) * 0.5f;

        h[k][0] = px; h[k][1] = py; h[k][2] = pz;
        h[k][15] = 1.0f;

        dense_level0_lds(sL0, xn0, xn1, xn2, h[k][3], h[k][4]);
        dense_level(gtab + 4096u,  32u, xn0, xn1, xn2, h[k][5], h[k][6]);
        dense_level(gtab + 36864u, 64u, xn0, xn1, xn2, h[k][7], h[k][8]);

        #pragma unroll
        for (int l = 0; l < 3; ++l) {
            const unsigned p = __builtin_nontemporal_load(
                feat + (size_t)l * N + gs);
            h[k][9 + 2 * l]  = bf2f_lo(p);
            h[k][10 + 2 * l] = bf2f_hi(p);
        }
    }

    // MLP: out = relu(h @ W0 + b0) @ W1 + b1 (bias folded via h[15]=1).
    const float b1v = wt[1088];
    float o[4] = {b1v, b1v, b1v, b1v};

    #pragma unroll 4
    for (int j = 0; j < 64; ++j) {
        float r[16];
        #pragma unroll
        for (int i = 0; i < 16; ++i)
            r[i] = wt[j * 16 + i];          // uniform -> s_load (SMEM pipe)
        const float w1j = wt[1024 + j];
        #pragma unroll
        for (int k = 0; k < 4; ++k) {
            float s = 0.0f;
            #pragma unroll
            for (int i = 0; i < 16; ++i)
                s = fmaf(h[k][i], r[i], s);  // v_fma with SGPR weight
            s = fmaxf(s, 0.0f);
            o[k] = fmaf(s, w1j, o[k]);
        }
    }

    #pragma unroll
    for (int k = 0; k < 4; ++k) {
        const int g = base + 256 * k;
        if (g < N) __builtin_nontemporal_store(o[k], out + g);
    }
}

extern "C" void kernel_launch(void* const* d_in, const int* in_sizes, int n_in,
                              void* d_out, int out_size, void* d_ws, size_t ws_size,
                              hipStream_t stream) {
    const float* x    = (const float*)d_in[0];
    const float* grid = (const float*)d_in[1];
    const float* W0   = (const float*)d_in[2];
    const float* b0   = (const float*)d_in[3];
    const float* W1   = (const float*)d_in[4];
    const float* b1   = (const float*)d_in[5];
    float* out = (float*)d_out;

    const int N = in_sizes[0] / 3;
    const int blocks2 = (N + 511) / 512;    // hash: 2 pts/thread
    const int blocks4 = (N + 1023) / 1024;  // dense_mlp: 4 pts/thread

    const float2* gtab = (const float2*)grid;
    unsigned* feat = (unsigned*)d_ws;                      // [3][N] bf16x2 = 24MB
    const size_t feat_bytes = ((size_t)3 * N * 4 + 255) & ~(size_t)255;
    float* wt = (float*)((char*)d_ws + feat_bytes);        // 1089 floats

    prep_kernel<<<1, 256, 0, stream>>>(W0, b0, W1, b1, wt);

    hash_level_kernel<<<blocks2, 256, 0, stream>>>(x, gtab + 299008u,
                                                   feat + (size_t)0 * N, 127.0f, N);
    hash_level_kernel<<<blocks2, 256, 0, stream>>>(x, gtab + 823296u,
                                                   feat + (size_t)1 * N, 255.0f, N);
    hash_level_kernel<<<blocks2, 256, 0, stream>>>(x, gtab + 1347584u,
                                                   feat + (size_t)2 * N, 511.0f, N);
    dense_mlp_kernel<<<blocks4, 256, 0, stream>>>(x, grid, feat, wt, out, N);
}